// Round 8
// baseline (331.248 us; speedup 1.0000x reference)
//
#include <hip/hip_runtime.h>
#include <hip/hip_bf16.h>
#include <stdint.h>

#define NN 100000
#define NE 1600000
#define NBLK 256                 // edge-chunk blocks (and k_build grid size)
#define EPB (NE / NBLK)          // 6250 edges per block
#define NBINS 782                // ceil(NN/128) coarse bins of 128 nodes
#define NCELL (NBINS * NBLK)     // 200192 scan cells
#define NSB ((NCELL + 1023) / 1024)  // 196 scan chunks
#define GEMMB 782                // gemm blocks: 3126 wave-tasks / 4 waves per block
#define BINCAP 4096              // LDS cache per bin (mean bin count 2046, sd ~45)

// ---------------- bf16 helpers ----------------

__device__ __forceinline__ unsigned pack_bf16(float a, float b) {
    unsigned ua = __float_as_uint(a);
    unsigned ub = __float_as_uint(b);
    ua += 0x7FFFu + ((ua >> 16) & 1u);       // RNE
    ub += 0x7FFFu + ((ub >> 16) & 1u);
    return (ua >> 16) | (ub & 0xFFFF0000u);  // a -> low half (element 2k)
}
#define BF_LO(u) __uint_as_float((u) << 16)
#define BF_HI(u) __uint_as_float((u) & 0xFFFF0000u)

// ---------------- edge_index width detection, inlined ----------------------

__device__ __forceinline__ int ei_is64(const int* __restrict__ ei) {
    int z = 0;
#pragma unroll
    for (int i = 0; i < 16; ++i) z |= ei[2 * i + 1];
    return z == 0;
}

// ---------------- grid barrier (device-scope, per-use counter) --------------
// 256 blocks x 1024 thr = 16 waves/block: 1 block/CU on 256 CUs with 2x
// capacity margin -> co-residency assured. Counters memset to 0 per launch.
// Thread-0 __threadfence() gives agent-scope wb/inv (the same visibility a
// kernel boundary provides); the whole block shares thread-0's CU caches.

__device__ __forceinline__ void gbar(int* bar, int id) {
    __syncthreads();
    if (threadIdx.x == 0) {
        __threadfence();
        __hip_atomic_fetch_add(&bar[id], 1, __ATOMIC_ACQ_REL, __HIP_MEMORY_SCOPE_AGENT);
        while (__hip_atomic_load(&bar[id], __ATOMIC_ACQUIRE, __HIP_MEMORY_SCOPE_AGENT) < NBLK) {}
        __threadfence();
    }
    __syncthreads();
}

// ---------------- fused CSR front-end: hist + scan + scan + scatter ---------
// R7: was 4 dependent dispatches streaming ei twice from HBM and bouncing
// gcount/goff through HBM. One kernel, 3 grid barriers; ei warm on re-read,
// scan arrays cache-resident. Scatter keeps the R5 LDS-cursor design (the
// goff column IS the cursor; chain = LDS-atomic -> store).

__global__ void __launch_bounds__(1024) k_build(const int* __restrict__ ei,
                                                int* __restrict__ gcount,
                                                int* __restrict__ bsum,
                                                int* __restrict__ goff,
                                                unsigned* __restrict__ tmp,
                                                int* __restrict__ bar) {
    __shared__ int lbin[NBINS];
    __shared__ int sh[256];
    __shared__ int boffs_sh;
    int t = threadIdx.x, blk = blockIdx.x;
    int is64 = ei_is64(ei);
    int e0 = blk * EPB;
    // ---- phase 1: per-(bin,chunk) histogram ----
    for (int i = t; i < NBINS; i += 1024) lbin[i] = 0;
    __syncthreads();
    if (is64) {
        const int2* p = (const int2*)ei;
        for (int e = e0 + t; e < e0 + EPB; e += 1024)
            atomicAdd(&lbin[p[NE + e].x >> 7], 1);
    } else {
        for (int e = e0 + t; e < e0 + EPB; e += 1024)
            atomicAdd(&lbin[ei[NE + e] >> 7], 1);
    }
    __syncthreads();
    for (int b = t; b < NBINS; b += 1024) gcount[b * NBLK + blk] = lbin[b];
    gbar(bar, 0);
    // ---- phase 2: sum of each 1024-cell chunk (chunks = blocks < NSB) ----
    if (blk < NSB) {
        if (t < 256) {
            int base = blk * 1024 + t * 4;
            int s = 0;
#pragma unroll
            for (int j = 0; j < 4; ++j) { int i = base + j; if (i < NCELL) s += gcount[i]; }
            sh[t] = s;
        }
        __syncthreads();
        for (int off = 128; off > 0; off >>= 1) {
            if (t < off) sh[t] += sh[t + off];
            __syncthreads();
        }
        if (t == 0) bsum[blk] = sh[0];
    }
    gbar(bar, 1);
    // ---- phase 3: exclusive scan -> goff (chunk offset rescanned per block) -
    if (blk < NSB) {
        int bv = 0;
        if (t < 256) { bv = (t < NSB) ? bsum[t] : 0; sh[t] = bv; }
        __syncthreads();
        for (int off = 1; off < 256; off <<= 1) {
            int tv = 0;
            if (t < 256 && t >= off) tv = sh[t - off];
            __syncthreads();
            if (t < 256) sh[t] += tv;
            __syncthreads();
        }
        if (t == blk) boffs_sh = sh[t] - bv;   // exclusive prefix of own chunk
        __syncthreads();
        int v[4]; int s = 0;
        int base = blk * 1024 + t * 4;
        if (t < 256) {
#pragma unroll
            for (int j = 0; j < 4; ++j) { int i = base + j; v[j] = (i < NCELL) ? gcount[i] : 0; s += v[j]; }
        }
        __syncthreads();
        if (t < 256) sh[t] = s;
        __syncthreads();
        for (int off = 1; off < 256; off <<= 1) {
            int tv = 0;
            if (t < 256 && t >= off) tv = sh[t - off];
            __syncthreads();
            if (t < 256) sh[t] += tv;
            __syncthreads();
        }
        if (t < 256) {
            int run = sh[t] - s + boffs_sh;
#pragma unroll
            for (int j = 0; j < 4; ++j) {
                int i = base + j;
                if (i < NCELL) { goff[i] = run; run += v[j]; }
            }
        }
    }
    gbar(bar, 2);
    // ---- phase 4: scatter, LDS cursors = final global positions ----
    for (int i = t; i < NBINS; i += 1024) lbin[i] = goff[i * NBLK + blk];
    __syncthreads();
    for (int e = e0 + t; e < e0 + EPB; e += 1024) {
        int s, d;
        if (is64) {
            s = ((const int2*)ei)[e].x;
            d = ((const int2*)ei)[NE + e].x;
        } else {
            s = ei[e];
            d = ei[NE + e];
        }
        int b = d >> 7;
        int pos = atomicAdd(&lbin[b], 1);
        tmp[pos] = (unsigned)s | ((unsigned)(d & 127) << 17);
    }
}

// ---------------- fp32 GEMM -> bf16 H body: H[N,64] = X[N,64] @ W[64,64] -----
// One task per wave: task = (64-row tile, 32-col half), acc[32] (no spill).
// task forced wave-uniform via readfirstlane so the W address is provably
// scalar -> compiler emits s_load for W.

__device__ __forceinline__ void gemm_body(int gb, const float* __restrict__ X,
                                          const float* __restrict__ W,
                                          unsigned* __restrict__ Hb) {
    int wid = (gb * 256 + (int)threadIdx.x) >> 6;
    int lane = threadIdx.x & 63;
    int task = __builtin_amdgcn_readfirstlane(wid);
    const int ntasks = ((NN + 63) >> 6) * 2;    // 1563 tiles x 2 col-halves = 3126
    if (task >= ntasks) return;
    int t = task >> 1;
    int ch = task & 1;                          // columns ch*32 .. ch*32+31 (scalar)
    int row = t * 64 + lane;
    int r = row < NN ? row : NN - 1;            // clamped lanes write duplicate data
    const float4* xp = (const float4*)(X + (size_t)r * 64);
    const float* Wb = W + ch * 32;              // scalar base
    float acc[32];
#pragma unroll
    for (int c = 0; c < 32; ++c) acc[c] = 0.f;
#pragma unroll 4
    for (int k4 = 0; k4 < 16; ++k4) {
        float4 xv = xp[k4];
#pragma unroll
        for (int kj = 0; kj < 4; ++kj) {
            float xk = (kj == 0) ? xv.x : (kj == 1) ? xv.y : (kj == 2) ? xv.z : xv.w;
            const float4* wr = (const float4*)(Wb + (k4 * 4 + kj) * 64);
#pragma unroll
            for (int c4 = 0; c4 < 8; ++c4) {
                float4 wv = wr[c4];
                acc[c4 * 4 + 0] += xk * wv.x;
                acc[c4 * 4 + 1] += xk * wv.y;
                acc[c4 * 4 + 2] += xk * wv.z;
                acc[c4 * 4 + 3] += xk * wv.w;
            }
        }
    }
    uint4* op = (uint4*)(Hb + (size_t)r * 32 + ch * 16);
#pragma unroll
    for (int q = 0; q < 4; ++q) {
        uint4 o;
        o.x = pack_bf16(acc[q * 8 + 0], acc[q * 8 + 1]);
        o.y = pack_bf16(acc[q * 8 + 2], acc[q * 8 + 3]);
        o.z = pack_bf16(acc[q * 8 + 4], acc[q * 8 + 5]);
        o.w = pack_bf16(acc[q * 8 + 6], acc[q * 8 + 7]);
        op[q] = o;
    }
}

__global__ void __launch_bounds__(256) k_gemm(const float* __restrict__ X,
                                              const float* __restrict__ W,
                                              unsigned* __restrict__ Hb) {
    gemm_body(blockIdx.x, X, W, Hb);
}

// ---------------- fused deg+csr (single tmp pass, LDS-cached) + gemm1 -------
// Blocks [0,NBINS): finalize CSR for one 128-node bin (tmp streamed once,
// LDS-cached). csr entry is just the src id; per-edge weight is gathered as
// dinv[src] in k_agg. Blocks [NBINS,NBINS+GEMMB): layer-1 GEMM co-launched.

__global__ void __launch_bounds__(256) k_degcsr_gemm(const unsigned* __restrict__ tmp,
                                                     const int* __restrict__ goff,
                                                     int* __restrict__ rs,
                                                     float* __restrict__ dinv,
                                                     unsigned* __restrict__ csr,
                                                     const float* __restrict__ X,
                                                     const float* __restrict__ W1,
                                                     unsigned* __restrict__ Hb) {
    if (blockIdx.x >= NBINS) {
        gemm_body((int)blockIdx.x - NBINS, X, W1, Hb);
        return;
    }
    __shared__ unsigned cache[BINCAP];
    __shared__ int hist[128];
    __shared__ int cur[128];
    __shared__ int base_sh[128];
    int b = blockIdx.x, t = threadIdx.x;
    if (t < 128) { hist[t] = 0; cur[t] = 0; }
    __syncthreads();
    int bs = goff[b * NBLK];
    int be = (b == NBINS - 1) ? NE : goff[(b + 1) * NBLK];
    for (int e = bs + t; e < be; e += 256) {
        unsigned v = tmp[e];
        int i = e - bs;
        if (i < BINCAP) cache[i] = v;
        atomicAdd(&hist[v >> 17], 1);
    }
    __syncthreads();
    if (t < 128) {
        int node = b * 128 + t;
        if (node < NN) {
            int c = hist[t];
            int loff = 0;
            for (int i = 0; i < t; ++i) loff += hist[i];
            rs[node] = bs + loff;
            base_sh[t] = bs + loff;
            dinv[node] = rsqrtf((float)c + 1.0f);
        } else base_sh[t] = 0;
    }
    if (b == 0 && t == 0) rs[NN] = NE;
    __syncthreads();
    int cnt = be - bs;
    for (int i = t; i < cnt; i += 256) {
        unsigned v = (i < BINCAP) ? cache[i] : tmp[bs + i];
        int dl = v >> 17;
        int lr = atomicAdd(&cur[dl], 1);
        csr[base_sh[dl] + lr] = v & 0x1FFFFu;   // plain src id
    }
}

// ---------------- aggregation: verified 8 edge-groups x 8 feature-lanes x
// uint4 shape (R6: uint2 reshape regressed; R7: fused GEMM epilogue regressed
// — k_agg is gather-latency-bound, leave the loop alone). 32-bit zext byte
// offsets -> saddr+voffset addressing.

#define EDGE_ACC(wt, r)                                                       \
    {                                                                         \
        a0 += BF_LO((r).x) * (wt); a1 += BF_HI((r).x) * (wt);                 \
        a2 += BF_LO((r).y) * (wt); a3 += BF_HI((r).y) * (wt);                 \
        a4 += BF_LO((r).z) * (wt); a5 += BF_HI((r).z) * (wt);                 \
        a6 += BF_LO((r).w) * (wt); a7 += BF_HI((r).w) * (wt);                 \
    }

__global__ void __launch_bounds__(256) k_agg(const unsigned* __restrict__ hb,
                                             const int* __restrict__ rs,
                                             const unsigned* __restrict__ csr,
                                             const float* __restrict__ dinv,
                                             const float* __restrict__ bias,
                                             float4* __restrict__ out4) {
    int wid = (blockIdx.x * blockDim.x + threadIdx.x) >> 6;
    int lane = threadIdx.x & 63;
    int node = __builtin_amdgcn_readfirstlane(wid);
    if (node >= NN) return;
    int g = lane >> 3;        // edge-stream group 0..7
    int s = lane & 7;         // feature octet 0..7
    const char* hbc = (const char*)hb;
    const char* dvc = (const char*)dinv;
    unsigned soff = (unsigned)s << 4;
    float dn = dinv[node];
    int e0 = rs[node], e1 = rs[node + 1];
    float a0 = 0.f, a1 = 0.f, a2 = 0.f, a3 = 0.f;
    float a4 = 0.f, a5 = 0.f, a6 = 0.f, a7 = 0.f;
    int e = e0 + g;
    unsigned p0 = csr[e];
    unsigned p1 = csr[e + 8];
    for (; e + 8 < e1; e += 16) {
        unsigned q0 = csr[e + 16];
        unsigned q1 = csr[e + 24];
        float w0 = *(const float*)(dvc + (size_t)(p0 << 2));
        float w1 = *(const float*)(dvc + (size_t)(p1 << 2));
        uint4 r0 = *(const uint4*)(hbc + (size_t)((p0 << 7) + soff));
        uint4 r1 = *(const uint4*)(hbc + (size_t)((p1 << 7) + soff));
        EDGE_ACC(w0, r0);
        EDGE_ACC(w1, r1);
        p0 = q0; p1 = q1;
    }
    if (e < e1) {
        float w0 = *(const float*)(dvc + (size_t)(p0 << 2));
        uint4 r0 = *(const uint4*)(hbc + (size_t)((p0 << 7) + soff));
        EDGE_ACC(w0, r0);
    }
#pragma unroll
    for (int m = 8; m <= 32; m <<= 1) {
        a0 += __shfl_xor(a0, m); a1 += __shfl_xor(a1, m);
        a2 += __shfl_xor(a2, m); a3 += __shfl_xor(a3, m);
        a4 += __shfl_xor(a4, m); a5 += __shfl_xor(a5, m);
        a6 += __shfl_xor(a6, m); a7 += __shfl_xor(a7, m);
    }
    if (lane < 8) {
        uint4 r = *(const uint4*)(hbc + (size_t)(((unsigned)node << 7) + soff));
        const float4* bp = (const float4*)(bias + s * 8);
        float4 b0 = bp[0], b1v = bp[1];
        float4 o0, o1;
        o0.x = fmaxf((a0 + BF_LO(r.x) * dn) * dn + b0.x, 0.f);
        o0.y = fmaxf((a1 + BF_HI(r.x) * dn) * dn + b0.y, 0.f);
        o0.z = fmaxf((a2 + BF_LO(r.y) * dn) * dn + b0.z, 0.f);
        o0.w = fmaxf((a3 + BF_HI(r.y) * dn) * dn + b0.w, 0.f);
        o1.x = fmaxf((a4 + BF_LO(r.z) * dn) * dn + b1v.x, 0.f);
        o1.y = fmaxf((a5 + BF_HI(r.z) * dn) * dn + b1v.y, 0.f);
        o1.z = fmaxf((a6 + BF_LO(r.w) * dn) * dn + b1v.z, 0.f);
        o1.w = fmaxf((a7 + BF_HI(r.w) * dn) * dn + b1v.w, 0.f);
        out4[(size_t)node * 16 + s * 2] = o0;
        out4[(size_t)node * 16 + s * 2 + 1] = o1;
    }
}

// ---------------- launch ----------------

extern "C" void kernel_launch(void* const* d_in, const int* in_sizes, int n_in,
                              void* d_out, int out_size, void* d_ws, size_t ws_size,
                              hipStream_t stream) {
    const float* x  = (const float*)d_in[0];            // [NN,64] fp32
    const int* ei   = (const int*)d_in[1];              // [2,NE] int32/int64 (detected)
    const float* W1 = (const float*)d_in[2];
    const float* b1 = (const float*)d_in[3];
    const float* W2 = (const float*)d_in[4];
    const float* b2 = (const float*)d_in[5];

    char* ws = (char*)d_ws;
    size_t off = 0;
    auto alloc = [&](size_t bytes) -> char* {
        char* p = ws + off;
        off = (off + bytes + 511) & ~(size_t)511;
        return p;
    };
    int*      bar   = (int*)alloc(64);                   // grid-barrier counters
    int*      gcount= (int*)alloc((size_t)NCELL * 4);    // 800 KB
    int*      goff  = (int*)alloc((size_t)NCELL * 4);    // 800 KB
    int*      bsum  = (int*)alloc((size_t)NSB * 4);
    unsigned* tmp   = (unsigned*)alloc((size_t)NE * 4);  // 6.4 MB
    unsigned* csr   = (unsigned*)alloc((size_t)NE * 4);  // 6.4 MB
    int*      rs    = (int*)alloc((size_t)(NN + 1) * 4);
    float*    dinv  = (float*)alloc((size_t)NN * 4);
    unsigned* hbuf  = (unsigned*)alloc((size_t)NN * 32 * 4);  // 12.8 MB bf16 h (128 B rows)
    float*    hmid  = (float*)d_out;                     // layer-1 fp32 act (reuse d_out)

    hipMemsetAsync(bar, 0, 64, stream);
    // fused CSR front-end (was hist + pscan1 + pscan23 + scatter)
    k_build<<<NBLK, 1024, 0, stream>>>(ei, gcount, bsum, goff, tmp, bar);
    // CSR finalize + layer-1 GEMM co-launched (independent work, common consumer)
    k_degcsr_gemm<<<NBINS + GEMMB, 256, 0, stream>>>(tmp, goff, rs, dinv, csr,
                                                     x, W1, hbuf);
    // layer 1: hmid(=d_out, fp32) = relu(agg(hbuf) + b1)
    k_agg<<<(NN * 64) / 256, 256, 0, stream>>>(hbuf, rs, csr, dinv, b1,
                                               (float4*)hmid);
    // layer 2: hbuf(bf16) = hmid @ W2 ; d_out = relu(agg(hbuf) + b2)
    k_gemm<<<GEMMB, 256, 0, stream>>>(hmid, W2, hbuf);
    k_agg<<<(NN * 64) / 256, 256, 0, stream>>>(hbuf, rs, csr, dinv, b2,
                                               (float4*)d_out);
}

// Round 9
// 231.257 us; speedup vs baseline: 1.4324x; 1.4324x over previous
//
#include <hip/hip_runtime.h>
#include <hip/hip_bf16.h>
#include <stdint.h>

#define NN 100000
#define NE 1600000
#define NBLK 256                 // edge-chunk blocks for hist/scatter
#define EPB (NE / NBLK)          // 6250 edges per block
#define NBINS 782                // ceil(NN/128) coarse bins of 128 nodes
#define NCELL (NBINS * NBLK)     // 200192 scan cells
#define NSB ((NCELL + 1023) / 1024)  // 196 scan blocks
#define GEMMB 782                // gemm blocks: 3126 wave-tasks / 4 waves per block
#define BINCAP 4096              // LDS cache per bin (mean bin count 2046, sd ~45)

// ---------------- bf16 helpers ----------------

__device__ __forceinline__ unsigned pack_bf16(float a, float b) {
    unsigned ua = __float_as_uint(a);
    unsigned ub = __float_as_uint(b);
    ua += 0x7FFFu + ((ua >> 16) & 1u);       // RNE
    ub += 0x7FFFu + ((ub >> 16) & 1u);
    return (ua >> 16) | (ub & 0xFFFF0000u);  // a -> low half (element 2k)
}
#define BF_LO(u) __uint_as_float((u) << 16)
#define BF_HI(u) __uint_as_float((u) & 0xFFFF0000u)

// ---------------- edge_index width detection, inlined ----------------------

__device__ __forceinline__ int ei_is64(const int* __restrict__ ei) {
    int z = 0;
#pragma unroll
    for (int i = 0; i < 16; ++i) z |= ei[2 * i + 1];
    return z == 0;
}

// ---------------- CSR build via 2-level counting sort (NO global atomics) ----
// R4: global atomic-return fill = 160us (coherence serialization). R8: fused
// grid-barrier build = 126us (cross-XCD spin). Split 4-kernel counting sort
// is the verified design. Scatter: goff column preloaded to LDS, LDS counter
// IS the global cursor (chain: LDS-atomic -> store only).

__global__ void __launch_bounds__(1024) k_hist(const int* __restrict__ ei,
                                               int* __restrict__ gcount) {
    __shared__ int lbin[NBINS];
    int t = threadIdx.x, blk = blockIdx.x;
    for (int i = t; i < NBINS; i += 1024) lbin[i] = 0;
    __syncthreads();
    int is64 = ei_is64(ei);
    int e0 = blk * EPB;
    if (is64) {
        const int2* p = (const int2*)ei;
        for (int e = e0 + t; e < e0 + EPB; e += 1024)
            atomicAdd(&lbin[p[NE + e].x >> 7], 1);
    } else {
        for (int e = e0 + t; e < e0 + EPB; e += 1024)
            atomicAdd(&lbin[ei[NE + e] >> 7], 1);
    }
    __syncthreads();
    for (int b = t; b < NBINS; b += 1024) gcount[b * NBLK + blk] = lbin[b];
}

__global__ void k_pscan1(const int* __restrict__ g, int* __restrict__ bsum) {
    __shared__ int sh[256];
    int t = threadIdx.x;
    int base = blockIdx.x * 1024 + t * 4;
    int s = 0;
#pragma unroll
    for (int j = 0; j < 4; ++j) { int i = base + j; if (i < NCELL) s += g[i]; }
    sh[t] = s; __syncthreads();
    for (int off = 128; off > 0; off >>= 1) {
        if (t < off) sh[t] += sh[t + off];
        __syncthreads();
    }
    if (t == 0) bsum[blockIdx.x] = sh[0];
}

// pscan2 fused into pscan3: each block redundantly scans the 196 block sums
// (784 B, trivial) to find its own offset -> one fewer dependent launch.
__global__ void k_pscan23(const int* __restrict__ g, const int* __restrict__ bsum,
                          int* __restrict__ goff) {
    __shared__ int sh[256];
    __shared__ int boffs;
    int t = threadIdx.x;
    int bv = (t < NSB) ? bsum[t] : 0;
    sh[t] = bv; __syncthreads();
    for (int off = 1; off < 256; off <<= 1) {
        int tmp = (t >= off) ? sh[t - off] : 0;
        __syncthreads();
        sh[t] += tmp;
        __syncthreads();
    }
    if (t == blockIdx.x) boffs = sh[t] - bv;   // exclusive prefix of own block
    __syncthreads();
    int base = blockIdx.x * 1024 + t * 4;
    int v[4]; int s = 0;
#pragma unroll
    for (int j = 0; j < 4; ++j) { int i = base + j; v[j] = (i < NCELL) ? g[i] : 0; s += v[j]; }
    __syncthreads();                           // sh reuse safe (scan loop done)
    sh[t] = s; __syncthreads();
    for (int off = 1; off < 256; off <<= 1) {
        int tmp = (t >= off) ? sh[t - off] : 0;
        __syncthreads();
        sh[t] += tmp;
        __syncthreads();
    }
    int run = sh[t] - s + boffs;
#pragma unroll
    for (int j = 0; j < 4; ++j) {
        int i = base + j;
        if (i < NCELL) { goff[i] = run; run += v[j]; }
    }
}

// tmp entry: src (17 bits) | d_low7 << 17.
__global__ void __launch_bounds__(1024) k_scatter(const int* __restrict__ ei,
                                                  const int* __restrict__ goff,
                                                  unsigned* __restrict__ tmp) {
    __shared__ int gpos[NBINS];
    int t = threadIdx.x, blk = blockIdx.x;
    for (int i = t; i < NBINS; i += 1024) gpos[i] = goff[i * NBLK + blk];
    __syncthreads();
    int is64 = ei_is64(ei);
    int e0 = blk * EPB;
    for (int e = e0 + t; e < e0 + EPB; e += 1024) {
        int s, d;
        if (is64) {
            s = ((const int2*)ei)[e].x;
            d = ((const int2*)ei)[NE + e].x;
        } else {
            s = ei[e];
            d = ei[NE + e];
        }
        int b = d >> 7;
        int pos = atomicAdd(&gpos[b], 1);
        tmp[pos] = (unsigned)s | ((unsigned)(d & 127) << 17);
    }
}

// ---------------- fp32 GEMM -> bf16 H body: H[N,64] = X[N,64] @ W[64,64] -----
// One task per wave: task = (64-row tile, 32-col half), acc[32] (no spill).
// task forced wave-uniform via readfirstlane so the W address is provably
// scalar -> compiler emits s_load for W.

__device__ __forceinline__ void gemm_body(int gb, const float* __restrict__ X,
                                          const float* __restrict__ W,
                                          unsigned* __restrict__ Hb) {
    int wid = (gb * 256 + (int)threadIdx.x) >> 6;
    int lane = threadIdx.x & 63;
    int task = __builtin_amdgcn_readfirstlane(wid);
    const int ntasks = ((NN + 63) >> 6) * 2;    // 1563 tiles x 2 col-halves = 3126
    if (task >= ntasks) return;
    int t = task >> 1;
    int ch = task & 1;                          // columns ch*32 .. ch*32+31 (scalar)
    int row = t * 64 + lane;
    int r = row < NN ? row : NN - 1;            // clamped lanes write duplicate data
    const float4* xp = (const float4*)(X + (size_t)r * 64);
    const float* Wb = W + ch * 32;              // scalar base
    float acc[32];
#pragma unroll
    for (int c = 0; c < 32; ++c) acc[c] = 0.f;
#pragma unroll 4
    for (int k4 = 0; k4 < 16; ++k4) {
        float4 xv = xp[k4];
#pragma unroll
        for (int kj = 0; kj < 4; ++kj) {
            float xk = (kj == 0) ? xv.x : (kj == 1) ? xv.y : (kj == 2) ? xv.z : xv.w;
            const float4* wr = (const float4*)(Wb + (k4 * 4 + kj) * 64);
#pragma unroll
            for (int c4 = 0; c4 < 8; ++c4) {
                float4 wv = wr[c4];
                acc[c4 * 4 + 0] += xk * wv.x;
                acc[c4 * 4 + 1] += xk * wv.y;
                acc[c4 * 4 + 2] += xk * wv.z;
                acc[c4 * 4 + 3] += xk * wv.w;
            }
        }
    }
    uint4* op = (uint4*)(Hb + (size_t)r * 32 + ch * 16);
#pragma unroll
    for (int q = 0; q < 4; ++q) {
        uint4 o;
        o.x = pack_bf16(acc[q * 8 + 0], acc[q * 8 + 1]);
        o.y = pack_bf16(acc[q * 8 + 2], acc[q * 8 + 3]);
        o.z = pack_bf16(acc[q * 8 + 4], acc[q * 8 + 5]);
        o.w = pack_bf16(acc[q * 8 + 6], acc[q * 8 + 7]);
        op[q] = o;
    }
}

__global__ void __launch_bounds__(256) k_gemm(const float* __restrict__ X,
                                              const float* __restrict__ W,
                                              unsigned* __restrict__ Hb) {
    gemm_body(blockIdx.x, X, W, Hb);
}

// ---------------- fused deg+csr (single tmp pass, LDS-cached) + gemm1 -------
// Blocks [0,NBINS): finalize CSR for one 128-node bin (tmp streamed once,
// LDS-cached). csr entry is just the src id; per-edge weight is gathered as
// dinv[src] in k_agg. Blocks [NBINS,NBINS+GEMMB): layer-1 GEMM co-launched.

__global__ void __launch_bounds__(256) k_degcsr_gemm(const unsigned* __restrict__ tmp,
                                                     const int* __restrict__ goff,
                                                     int* __restrict__ rs,
                                                     float* __restrict__ dinv,
                                                     unsigned* __restrict__ csr,
                                                     const float* __restrict__ X,
                                                     const float* __restrict__ W1,
                                                     unsigned* __restrict__ Hb) {
    if (blockIdx.x >= NBINS) {
        gemm_body((int)blockIdx.x - NBINS, X, W1, Hb);
        return;
    }
    __shared__ unsigned cache[BINCAP];
    __shared__ int hist[128];
    __shared__ int cur[128];
    __shared__ int base_sh[128];
    int b = blockIdx.x, t = threadIdx.x;
    if (t < 128) { hist[t] = 0; cur[t] = 0; }
    __syncthreads();
    int bs = goff[b * NBLK];
    int be = (b == NBINS - 1) ? NE : goff[(b + 1) * NBLK];
    for (int e = bs + t; e < be; e += 256) {
        unsigned v = tmp[e];
        int i = e - bs;
        if (i < BINCAP) cache[i] = v;
        atomicAdd(&hist[v >> 17], 1);
    }
    __syncthreads();
    if (t < 128) {
        int node = b * 128 + t;
        if (node < NN) {
            int c = hist[t];
            int loff = 0;
            for (int i = 0; i < t; ++i) loff += hist[i];
            rs[node] = bs + loff;
            base_sh[t] = bs + loff;
            dinv[node] = rsqrtf((float)c + 1.0f);
        } else base_sh[t] = 0;
    }
    if (b == 0 && t == 0) rs[NN] = NE;
    __syncthreads();
    int cnt = be - bs;
    for (int i = t; i < cnt; i += 256) {
        unsigned v = (i < BINCAP) ? cache[i] : tmp[bs + i];
        int dl = v >> 17;
        int lr = atomicAdd(&cur[dl], 1);
        csr[base_sh[dl] + lr] = v & 0x1FFFFu;   // plain src id
    }
}

// ---------------- aggregation, R8: TWO nodes per wave -----------------------
// k_agg is prologue-latency-bound (R6: not VALU; R7: not write-traffic; 43us
// with nothing saturated). Half-wave h owns node 2*wid+h: per node 4 edge
// groups x 8 feature lanes, uint4 16B gathers (R6-verified width), 2-deep csr
// pipeline -> 8 edges in flight per node, 16 per wave (same request count as
// R5). The two nodes' rs->csr->gather chains issue CONCURRENTLY in one wave,
// halving effective prologue latency per node; wave count halves to 50K.
// Reduction: 2 shfl levels (xor 8,16 — stays within the half-wave).

#define EDGE_ACC(wt, r)                                                       \
    {                                                                         \
        a0 += BF_LO((r).x) * (wt); a1 += BF_HI((r).x) * (wt);                 \
        a2 += BF_LO((r).y) * (wt); a3 += BF_HI((r).y) * (wt);                 \
        a4 += BF_LO((r).z) * (wt); a5 += BF_HI((r).z) * (wt);                 \
        a6 += BF_LO((r).w) * (wt); a7 += BF_HI((r).w) * (wt);                 \
    }

__global__ void __launch_bounds__(256) k_agg(const unsigned* __restrict__ hb,
                                             const int* __restrict__ rs,
                                             const unsigned* __restrict__ csr,
                                             const float* __restrict__ dinv,
                                             const float* __restrict__ bias,
                                             float4* __restrict__ out4) {
    int wid = (blockIdx.x * blockDim.x + threadIdx.x) >> 6;
    int lane = threadIdx.x & 63;
    int node = wid * 2 + (lane >> 5);          // half-wave owns one node
    if (node >= NN) return;
    int g = (lane >> 3) & 3;  // edge-stream group 0..3 within half-wave
    int s = lane & 7;         // feature octet 0..7
    const char* hbc = (const char*)hb;
    const char* dvc = (const char*)dinv;
    unsigned soff = (unsigned)s << 4;
    float dn = dinv[node];
    int e0 = rs[node], e1 = rs[node + 1];
    float a0 = 0.f, a1 = 0.f, a2 = 0.f, a3 = 0.f;
    float a4 = 0.f, a5 = 0.f, a6 = 0.f, a7 = 0.f;
    int e = e0 + g;
    unsigned p0 = csr[e];
    unsigned p1 = csr[e + 4];
    for (; e + 4 < e1; e += 8) {
        unsigned q0 = csr[e + 8];
        unsigned q1 = csr[e + 12];
        float w0 = *(const float*)(dvc + (size_t)(p0 << 2));
        float w1 = *(const float*)(dvc + (size_t)(p1 << 2));
        uint4 r0 = *(const uint4*)(hbc + (size_t)((p0 << 7) + soff));
        uint4 r1 = *(const uint4*)(hbc + (size_t)((p1 << 7) + soff));
        EDGE_ACC(w0, r0);
        EDGE_ACC(w1, r1);
        p0 = q0; p1 = q1;
    }
    if (e < e1) {
        float w0 = *(const float*)(dvc + (size_t)(p0 << 2));
        uint4 r0 = *(const uint4*)(hbc + (size_t)((p0 << 7) + soff));
        EDGE_ACC(w0, r0);
    }
    // reduce across the 4 groups (lane bits 3,4) — stays within half-wave
#pragma unroll
    for (int m = 8; m <= 16; m <<= 1) {
        a0 += __shfl_xor(a0, m); a1 += __shfl_xor(a1, m);
        a2 += __shfl_xor(a2, m); a3 += __shfl_xor(a3, m);
        a4 += __shfl_xor(a4, m); a5 += __shfl_xor(a5, m);
        a6 += __shfl_xor(a6, m); a7 += __shfl_xor(a7, m);
    }
    if ((lane & 31) < 8) {
        uint4 r = *(const uint4*)(hbc + (size_t)(((unsigned)node << 7) + soff));
        const float4* bp = (const float4*)(bias + s * 8);
        float4 b0 = bp[0], b1v = bp[1];
        float4 o0, o1;
        o0.x = fmaxf((a0 + BF_LO(r.x) * dn) * dn + b0.x, 0.f);
        o0.y = fmaxf((a1 + BF_HI(r.x) * dn) * dn + b0.y, 0.f);
        o0.z = fmaxf((a2 + BF_LO(r.y) * dn) * dn + b0.z, 0.f);
        o0.w = fmaxf((a3 + BF_HI(r.y) * dn) * dn + b0.w, 0.f);
        o1.x = fmaxf((a4 + BF_LO(r.z) * dn) * dn + b1v.x, 0.f);
        o1.y = fmaxf((a5 + BF_HI(r.z) * dn) * dn + b1v.y, 0.f);
        o1.z = fmaxf((a6 + BF_LO(r.w) * dn) * dn + b1v.z, 0.f);
        o1.w = fmaxf((a7 + BF_HI(r.w) * dn) * dn + b1v.w, 0.f);
        out4[(size_t)node * 16 + s * 2] = o0;
        out4[(size_t)node * 16 + s * 2 + 1] = o1;
    }
}

// ---------------- launch ----------------

extern "C" void kernel_launch(void* const* d_in, const int* in_sizes, int n_in,
                              void* d_out, int out_size, void* d_ws, size_t ws_size,
                              hipStream_t stream) {
    const float* x  = (const float*)d_in[0];            // [NN,64] fp32
    const int* ei   = (const int*)d_in[1];              // [2,NE] int32/int64 (detected)
    const float* W1 = (const float*)d_in[2];
    const float* b1 = (const float*)d_in[3];
    const float* W2 = (const float*)d_in[4];
    const float* b2 = (const float*)d_in[5];

    char* ws = (char*)d_ws;
    size_t off = 0;
    auto alloc = [&](size_t bytes) -> char* {
        char* p = ws + off;
        off = (off + bytes + 511) & ~(size_t)511;
        return p;
    };
    int*      gcount= (int*)alloc((size_t)NCELL * 4);    // 800 KB
    int*      goff  = (int*)alloc((size_t)NCELL * 4);    // 800 KB
    int*      bsum  = (int*)alloc((size_t)NSB * 4);
    unsigned* tmp   = (unsigned*)alloc((size_t)NE * 4);  // 6.4 MB
    unsigned* csr   = (unsigned*)alloc((size_t)NE * 4);  // 6.4 MB
    int*      rs    = (int*)alloc((size_t)(NN + 1) * 4);
    float*    dinv  = (float*)alloc((size_t)NN * 4);
    unsigned* hbuf  = (unsigned*)alloc((size_t)NN * 32 * 4);  // 12.8 MB bf16 h (128 B rows)
    float*    hmid  = (float*)d_out;                     // layer-1 fp32 act (reuse d_out)

    k_hist<<<NBLK, 1024, 0, stream>>>(ei, gcount);
    k_pscan1<<<NSB, 256, 0, stream>>>(gcount, bsum);
    k_pscan23<<<NSB, 256, 0, stream>>>(gcount, bsum, goff);
    k_scatter<<<NBLK, 1024, 0, stream>>>(ei, goff, tmp);
    // CSR finalize + layer-1 GEMM co-launched (independent work, common consumer)
    k_degcsr_gemm<<<NBINS + GEMMB, 256, 0, stream>>>(tmp, goff, rs, dinv, csr,
                                                     x, W1, hbuf);
    // layer 1: hmid(=d_out, fp32) = relu(agg(hbuf) + b1)  [2 nodes/wave -> 12500 blocks]
    k_agg<<<(NN / 2) * 64 / 256, 256, 0, stream>>>(hbuf, rs, csr, dinv, b1,
                                                   (float4*)hmid);
    // layer 2: hbuf(bf16) = hmid @ W2 ; d_out = relu(agg(hbuf) + b2)
    k_gemm<<<GEMMB, 256, 0, stream>>>(hmid, W2, hbuf);
    k_agg<<<(NN / 2) * 64 / 256, 256, 0, stream>>>(hbuf, rs, csr, dinv, b2,
                                                   (float4*)d_out);
}